// Round 9
// baseline (415.343 us; speedup 1.0000x reference)
//
#include <hip/hip_runtime.h>
#include <hip/hip_bf16.h>

#define N_NODES 122880
#define N_EDGES 983040
#define NBKT 480      // buckets of 256 nodes
#define BCAP 2560     // per-bucket edge capacity (mean 2048, +11 sigma)
#define EPB 4096      // edges per pass-1 block

typedef __hip_bfloat16 bf16;
typedef __attribute__((ext_vector_type(8))) short short8;
typedef __attribute__((ext_vector_type(4))) float floatx4;

__device__ __forceinline__ void gl_lds16(const void* g, void* l) {
    __builtin_amdgcn_global_load_lds(
        (const __attribute__((address_space(1))) void*)g,
        (__attribute__((address_space(3))) void*)l, 16, 0, 0);
}

__device__ __forceinline__ float bflo(unsigned u) {
    return __uint_as_float(u << 16);
}
__device__ __forceinline__ float bfhi(unsigned u) {
    return __uint_as_float(u & 0xffff0000u);
}

// ---------------- pass 1: block-local bucket sort of edges ----------------
__global__ __launch_bounds__(256) void k_psort(const int* __restrict__ ei,
                                               int* __restrict__ gcur,
                                               unsigned* __restrict__ gbuf) {
    __shared__ int cur[NBKT];
    __shared__ int gb[NBKT];
    const int t = threadIdx.x;
    for (int i = t; i < NBKT; i += 256) cur[i] = 0;
    __syncthreads();
    const int base = blockIdx.x * EPB;
    unsigned pay[16];
    short bk[16], pib[16];
#pragma unroll
    for (int j = 0; j < 16; ++j) {
        int e = base + j * 256 + t;
        int d = ei[N_EDGES + e];
        int s = ei[e];
        bk[j] = (short)(d >> 8);
        pay[j] = (unsigned)(d & 255) | ((unsigned)s << 8);
        pib[j] = (short)atomicAdd(&cur[d >> 8], 1);
    }
    __syncthreads();
    for (int i = t; i < NBKT; i += 256) {
        int c = cur[i];
        gb[i] = c ? atomicAdd(&gcur[i * 16], c) : 0;  // line-padded cursor
    }
    __syncthreads();
#pragma unroll
    for (int j = 0; j < 16; ++j) {
        int pos = gb[bk[j]] + pib[j];
        if (pos < BCAP) gbuf[bk[j] * BCAP + pos] = pay[j];
    }
}

// ---------------- pass 2: per-bucket CSR build (+ dinv, fused) ----------------
__global__ __launch_bounds__(256) void k_bcsr(const int* __restrict__ gcur,
                                              const unsigned* __restrict__ gbuf,
                                              int* __restrict__ adj,
                                              unsigned* __restrict__ co,
                                              float* __restrict__ dinv) {
    __shared__ int hist[256];
    __shared__ int arr[256];
    __shared__ int exc[256];
    const int b = blockIdx.x, t = threadIdx.x;
    hist[t] = 0;
    __syncthreads();
    int E = gcur[b * 16];
    if (E > BCAP) E = BCAP;
    int dl[10], sv[10];
    short pb[10];
    int n = 0;
    for (int idx = t; idx < E; idx += 256) {
        unsigned p = gbuf[b * BCAP + idx];
        dl[n] = p & 255;
        sv[n] = (int)(p >> 8);
        pb[n] = (short)atomicAdd(&hist[dl[n]], 1);
        ++n;
    }
    __syncthreads();
    const int cnt_t = hist[t];
    arr[t] = cnt_t;
    __syncthreads();
    for (int d = 1; d < 256; d <<= 1) {      // Hillis-Steele inclusive scan
        int v = (t >= d) ? arr[t - d] : 0;
        __syncthreads();
        arr[t] += v;
        __syncthreads();
    }
    const int ex = arr[t] - cnt_t;           // exclusive offset
    exc[t] = ex;
    const int node = b * 256 + t;
    co[node] = ((unsigned)ex << 16) | (unsigned)cnt_t;
    dinv[node] = rsqrtf((float)cnt_t + 1.0f);
    __syncthreads();
    for (int j = 0; j < n; ++j)
        adj[b * BCAP + exc[dl[j]] + pb[j]] = sv[j];
}

// ---------------- x f32 -> bf16 copy (4 elems/thread) ----------------
__global__ __launch_bounds__(256) void k_xtobf(const float* __restrict__ x,
                                               bf16* __restrict__ xb) {
    int t = blockIdx.x * 256 + threadIdx.x;
    const float4 v = ((const float4*)x)[t];
    bf16* o = xb + t * 4;
    o[0] = __float2bfloat16(v.x);
    o[1] = __float2bfloat16(v.y);
    o[2] = __float2bfloat16(v.z);
    o[3] = __float2bfloat16(v.w);
}

// ---------------- weight conversion (f32 -> bf16, transposed) ----------------
__global__ __launch_bounds__(256) void k_convw(const float* __restrict__ W1,
                                               const float* __restrict__ W2,
                                               bf16* __restrict__ W1T,
                                               bf16* __restrict__ W2T) {
    int t = blockIdx.x * 256 + threadIdx.x;
    if (t < 64 * 128) {                 // W1 [64][128] -> W1T [128][64]
        int k = t >> 7, n = t & 127;
        W1T[n * 64 + k] = __float2bfloat16(W1[t]);
    } else {                            // W2 [128][64] -> W2T [64][128]
        int u = t - 64 * 128;
        int k = u >> 6, n = u & 63;
        W2T[n * 128 + k] = __float2bfloat16(W2[u]);
    }
}

// Wfc [1920][1728] f32 -> WfcT [1728][1920] bf16
__global__ __launch_bounds__(256) void k_transWfc(const float* __restrict__ W,
                                                  bf16* __restrict__ WT) {
    __shared__ float t[32][33];
    int tx = threadIdx.x, ty = threadIdx.y;
    int n0 = blockIdx.x * 32, k0 = blockIdx.y * 32;
#pragma unroll
    for (int j = 0; j < 4; ++j)
        t[ty + j * 8][tx] = W[(long)(k0 + ty + j * 8) * 1728 + n0 + tx];
    __syncthreads();
#pragma unroll
    for (int j = 0; j < 4; ++j)
        WT[(long)(n0 + ty + j * 8) * 1920 + k0 + tx] =
            __float2bfloat16(t[tx][ty + j * 8]);
}

// ---------------- aggregation (unchanged) ----------------
template <bool BIAS_RELU>
__global__ __launch_bounds__(256) void k_agg(const bf16* __restrict__ xb,
                                             const float* __restrict__ dinv,
                                             const unsigned* __restrict__ co,
                                             const int* __restrict__ adj,
                                             const float* __restrict__ bias,
                                             bf16* __restrict__ out) {
    const int wave = threadIdx.x >> 6, lane = threadIdx.x & 63;
    const int half = lane >> 5, l32 = lane & 31;
    const int node = blockIdx.x * 8 + wave * 2 + half;

    const float di = dinv[node];
    const unsigned c_ = co[node];
    int c = (int)(c_ & 0xffffu);
    if (c > 32) c = 32;
    const int* al = adj + (node >> 8) * BCAP + (c_ >> 16);
    int   sl = (l32 < c) ? al[l32]  : 0;
    float wl = (l32 < c) ? dinv[sl] : 0.0f;

    const unsigned us = *(const unsigned*)(xb + ((long)node << 6) + (l32 << 1));
    float acc0 = di * bflo(us);
    float acc1 = di * bfhi(us);

    for (int p0 = 0; p0 < c; p0 += 8) {
        unsigned uu[8];
        float w8[8];
#pragma unroll
        for (int j = 0; j < 8; ++j) {
            int p = p0 + j;
            bool ok = p < c;
            int s = ok ? __shfl(sl, p, 32) : 0;
            w8[j] = ok ? __shfl(wl, p, 32) : 0.0f;
            uu[j] = *(const unsigned*)(xb + ((long)s << 6) + (l32 << 1));
        }
#pragma unroll
        for (int j = 0; j < 8; ++j) {
            acc0 += w8[j] * bflo(uu[j]);
            acc1 += w8[j] * bfhi(uu[j]);
        }
    }

    float r0 = di * acc0, r1 = di * acc1;
    if (BIAS_RELU) {
        r0 = fmaxf(r0 + bias[l32 * 2], 0.0f);
        r1 = fmaxf(r1 + bias[l32 * 2 + 1], 0.0f);
    }
    bf16* o = out + ((long)node << 6) + (l32 << 1);
    o[0] = __float2bfloat16(r0);
    o[1] = __float2bfloat16(r1);
}

// ---------------- fused MLP: g = relu(xa@W1 + b1) @ W2 ----------------
__global__ __launch_bounds__(256) void k_mlp(const bf16* __restrict__ xa,
                                             const bf16* __restrict__ W1T,
                                             const bf16* __restrict__ W2T,
                                             const float* __restrict__ b1,
                                             bf16* __restrict__ g) {
    __shared__ __align__(16) bf16 As[128 * 64];    // row&7 chunk-XOR swizzle
    __shared__ __align__(16) bf16 C1s[128 * 136];
    const int tid = threadIdx.x;
    const int wave = tid >> 6, lane = tid & 63;
    const int quad = lane >> 4, l16 = lane & 15;
    const int bm = blockIdx.x * 128;
    const int wm = (wave & 1) * 64;
    const int wn1 = (wave >> 1) * 64;
    const int wn2 = (wave >> 1) * 32;

#pragma unroll
    for (int q = 0; q < 4; ++q) {
        int G = q * 256 + tid;
        int gc = (G & ~7) | ((G & 7) ^ ((G >> 3) & 7));
        gl_lds16(xa + (long)bm * 64 + gc * 8, As + ((q * 4 + wave) * 64) * 8);
    }
    short8 w1f[2][4];
#pragma unroll
    for (int kc = 0; kc < 2; ++kc)
#pragma unroll
        for (int in = 0; in < 4; ++in)
            w1f[kc][in] = *(const short8*)(W1T + (wn1 + in * 16 + l16) * 64 +
                                           kc * 32 + quad * 8);
    floatx4 acc1[4][4];
#pragma unroll
    for (int i = 0; i < 4; ++i)
#pragma unroll
        for (int j = 0; j < 4; ++j) acc1[i][j] = (floatx4){0.f, 0.f, 0.f, 0.f};
    __syncthreads();

#pragma unroll
    for (int kc = 0; kc < 2; ++kc)
#pragma unroll
        for (int im = 0; im < 4; ++im) {
            const int R = wm + im * 16 + l16;
            short8 af = *(const short8*)(As + R * 64 +
                                         (((kc * 4 + quad) ^ (R & 7)) * 8));
#pragma unroll
            for (int in = 0; in < 4; ++in)
                acc1[im][in] = __builtin_amdgcn_mfma_f32_16x16x32_bf16(
                    af, w1f[kc][in], acc1[im][in], 0, 0, 0);
        }

#pragma unroll
    for (int in = 0; in < 4; ++in) {
        const int col = wn1 + in * 16 + l16;
        const float bv = b1[col];
#pragma unroll
        for (int im = 0; im < 4; ++im) {
            const int row = wm + im * 16 + quad * 4;
#pragma unroll
            for (int r = 0; r < 4; ++r)
                C1s[(row + r) * 136 + col] =
                    __float2bfloat16(fmaxf(acc1[im][in][r] + bv, 0.0f));
        }
    }
    short8 w2f[4][2];
#pragma unroll
    for (int kc = 0; kc < 4; ++kc)
#pragma unroll
        for (int in = 0; in < 2; ++in)
            w2f[kc][in] = *(const short8*)(W2T + (wn2 + in * 16 + l16) * 128 +
                                           kc * 32 + quad * 8);
    floatx4 acc2[4][2];
#pragma unroll
    for (int i = 0; i < 4; ++i)
#pragma unroll
        for (int j = 0; j < 2; ++j) acc2[i][j] = (floatx4){0.f, 0.f, 0.f, 0.f};
    __syncthreads();

#pragma unroll
    for (int kc = 0; kc < 4; ++kc)
#pragma unroll
        for (int im = 0; im < 4; ++im) {
            short8 af = *(const short8*)(C1s + (wm + im * 16 + l16) * 136 +
                                         kc * 32 + quad * 8);
#pragma unroll
            for (int in = 0; in < 2; ++in)
                acc2[im][in] = __builtin_amdgcn_mfma_f32_16x16x32_bf16(
                    af, w2f[kc][in], acc2[im][in], 0, 0, 0);
        }

#pragma unroll
    for (int in = 0; in < 2; ++in) {
        const int col = wn2 + in * 16 + l16;
#pragma unroll
        for (int im = 0; im < 4; ++im) {
            const int row = bm + wm + im * 16 + quad * 4;
#pragma unroll
            for (int r = 0; r < 4; ++r)
                g[(long)(row + r) * 64 + col] = __float2bfloat16(acc2[im][in][r]);
        }
    }
}

// ---------------- bf16 MFMA GEMM, depth-2 register pipeline ----------------
// C[M,N] = A[M,K] @ BT[N,K]^T. BM=128, BN=64, BK=32, K % 64 == 0.
// K-loop unrolled by 2 with two independent register buffers: loads issued in
// body i are consumed (ds_write) in body i+2 -> vmcnt wait covered by ~1.5
// bodies of MFMA/ds work (>= LLC hit latency), no register rotate.
template <bool RELU, bool BIAS, typename OutT>
__global__ __launch_bounds__(256) void gemm_bt(const bf16* __restrict__ A,
                                               const bf16* __restrict__ BT,
                                               const float* __restrict__ bias,
                                               OutT* __restrict__ C,
                                               int M, int N, int K) {
    __shared__ __align__(16) bf16 As[128 * 32];
    __shared__ __align__(16) bf16 Bs[64 * 32];
    const int tid = threadIdx.x;
    const int wave = tid >> 6, lane = tid & 63;
    const int quad = lane >> 4, l16 = lane & 15;
    const int bm = blockIdx.x * 128, bn = blockIdx.y * 64;
    const int wm = (wave & 1) * 64, wn = (wave >> 1) * 32;

    floatx4 acc[4][2];
#pragma unroll
    for (int i = 0; i < 4; ++i)
#pragma unroll
        for (int j = 0; j < 2; ++j) acc[i][j] = (floatx4){0.f, 0.f, 0.f, 0.f};

    const int r4 = tid >> 2;   // row 0..63 within half-tile
    const int cc = tid & 3;    // linear global chunk
    const int slot = r4 * 32 + ((cc ^ ((r4 >> 1) & 3)) * 8);  // swizzled (shorts)

    const bf16* gA0 = A + (long)(bm + r4) * K + cc * 8;
    const bf16* gA1 = A + (long)(bm + r4 + 64) * K + cc * 8;
    const bf16* gB  = BT + (long)(bn + r4) * K + cc * 8;

    uint4 pre[2][3];
#pragma unroll
    for (int h = 0; h < 2; ++h) {
        pre[h][0] = *(const uint4*)(gA0 + h * 32);
        pre[h][1] = *(const uint4*)(gA1 + h * 32);
        pre[h][2] = *(const uint4*)(gB + h * 32);
    }

    const int rsw = (l16 >> 1) & 3;

    for (int k0 = 0; k0 < K; k0 += 64) {
#pragma unroll
        for (int h = 0; h < 2; ++h) {
            *(uint4*)(As + slot) = pre[h][0];
            *(uint4*)(As + 2048 + slot) = pre[h][1];
            *(uint4*)(Bs + slot) = pre[h][2];
            __syncthreads();
            const int kn = k0 + h * 32 + 64;   // 2 bodies ahead
            if (kn < K) {
                pre[h][0] = *(const uint4*)(gA0 + kn);
                pre[h][1] = *(const uint4*)(gA1 + kn);
                pre[h][2] = *(const uint4*)(gB + kn);
            }
            short8 af[4], bfr[2];
#pragma unroll
            for (int im = 0; im < 4; ++im)
                af[im] = *(const short8*)(As + (wm + im * 16 + l16) * 32 +
                                          (quad ^ rsw) * 8);
#pragma unroll
            for (int in = 0; in < 2; ++in)
                bfr[in] = *(const short8*)(Bs + (wn + in * 16 + l16) * 32 +
                                           (quad ^ rsw) * 8);
#pragma unroll
            for (int im = 0; im < 4; ++im)
#pragma unroll
                for (int in = 0; in < 2; ++in)
                    acc[im][in] = __builtin_amdgcn_mfma_f32_16x16x32_bf16(
                        af[im], bfr[in], acc[im][in], 0, 0, 0);
            __syncthreads();
        }
    }

#pragma unroll
    for (int in = 0; in < 2; ++in) {
        int gcol = bn + wn + in * 16 + l16;
        float bv = BIAS ? bias[gcol] : 0.0f;
#pragma unroll
        for (int im = 0; im < 4; ++im) {
            int mrow = bm + wm + im * 16 + quad * 4;
#pragma unroll
            for (int r = 0; r < 4; ++r) {
                float v = acc[im][in][r] + bv;
                if (RELU) v = fmaxf(v, 0.0f);
                if constexpr (sizeof(OutT) == 2)
                    C[(long)(mrow + r) * N + gcol] = __float2bfloat16(v);
                else
                    C[(long)(mrow + r) * N + gcol] = v;
            }
        }
    }
}

// ---------------- driver ----------------
extern "C" void kernel_launch(void* const* d_in, const int* in_sizes, int n_in,
                              void* d_out, int out_size, void* d_ws, size_t ws_size,
                              hipStream_t stream) {
    const float* x   = (const float*)d_in[0];
    const int*   ei  = (const int*)d_in[1];
    const float* W1  = (const float*)d_in[2];
    const float* b1  = (const float*)d_in[3];
    const float* W2  = (const float*)d_in[4];
    const float* b2  = (const float*)d_in[5];
    const float* Wfc = (const float*)d_in[6];
    const float* bfc = (const float*)d_in[7];

    char* p = (char*)d_ws;
    int*      gcur = (int*)p;      p += (size_t)NBKT * 16 * 4;
    unsigned* gbuf = (unsigned*)p; p += (size_t)NBKT * BCAP * 4;
    int*      adj  = (int*)p;      p += (size_t)NBKT * BCAP * 4;
    unsigned* co   = (unsigned*)p; p += (size_t)N_NODES * 4;
    float*    dinv = (float*)p;    p += (size_t)N_NODES * 4;
    bf16*     xb   = (bf16*)p;     p += (size_t)N_NODES * 64 * 2;
    bf16*     xa   = (bf16*)p;     p += (size_t)N_NODES * 64 * 2;
    bf16*     g    = (bf16*)p;     p += (size_t)N_NODES * 64 * 2;
    bf16*     h2   = (bf16*)p;     p += (size_t)N_NODES * 64 * 2;
    bf16*     W1T  = (bf16*)p;     p += 128 * 64 * 2;
    bf16*     W2T  = (bf16*)p;     p += 64 * 128 * 2;
    bf16*     WfcT = (bf16*)p;     p += (size_t)1728 * 1920 * 2;

    hipMemsetAsync(gcur, 0, (size_t)NBKT * 16 * 4, stream);
    k_psort<<<N_EDGES / EPB, 256, 0, stream>>>(ei, gcur, gbuf);
    k_bcsr<<<NBKT, 256, 0, stream>>>(gcur, gbuf, adj, co, dinv);
    k_xtobf<<<N_NODES * 64 / 4 / 256, 256, 0, stream>>>(x, xb);
    k_convw<<<64, 256, 0, stream>>>(W1, W2, W1T, W2T);
    k_transWfc<<<dim3(54, 60), dim3(32, 8), 0, stream>>>(Wfc, WfcT);

    // xa = A_hat * x
    k_agg<false><<<N_NODES / 8, 256, 0, stream>>>(xb, dinv, co, adj, nullptr, xa);
    // g = relu(xa@W1 + b1) @ W2   (fused, h1 never touches HBM)
    k_mlp<<<N_NODES / 128, 256, 0, stream>>>(xa, W1T, W2T, b1, g);
    // h2 = relu(A_hat * g + b2)
    k_agg<true><<<N_NODES / 8, 256, 0, stream>>>(g, dinv, co, adj, b2, h2);
    // out = h2.reshape(4096,1920) @ Wfc + bfc
    gemm_bt<false, true, float><<<dim3(32, 27), 256, 0, stream>>>(
        h2, WfcT, bfc, (float*)d_out, 4096, 1728, 1920);
}

// Round 10
// 245.537 us; speedup vs baseline: 1.6916x; 1.6916x over previous
//
#include <hip/hip_runtime.h>
#include <hip/hip_bf16.h>

#define N_NODES 122880
#define N_EDGES 983040
#define NBKT 480      // buckets of 256 nodes
#define BCAP 2560     // per-bucket edge capacity (mean 2048, +11 sigma)
#define EPB 4096      // edges per pass-1 block

typedef __hip_bfloat16 bf16;
typedef __attribute__((ext_vector_type(8))) short short8;
typedef __attribute__((ext_vector_type(4))) float floatx4;

__device__ __forceinline__ void gl_lds16(const void* g, void* l) {
    __builtin_amdgcn_global_load_lds(
        (const __attribute__((address_space(1))) void*)g,
        (__attribute__((address_space(3))) void*)l, 16, 0, 0);
}

__device__ __forceinline__ float bflo(unsigned u) {
    return __uint_as_float(u << 16);
}
__device__ __forceinline__ float bfhi(unsigned u) {
    return __uint_as_float(u & 0xffff0000u);
}

// ---------------- pass 1: block-local bucket sort of edges ----------------
__global__ __launch_bounds__(256) void k_psort(const int* __restrict__ ei,
                                               int* __restrict__ gcur,
                                               unsigned* __restrict__ gbuf) {
    __shared__ int cur[NBKT];
    __shared__ int gb[NBKT];
    const int t = threadIdx.x;
    for (int i = t; i < NBKT; i += 256) cur[i] = 0;
    __syncthreads();
    const int base = blockIdx.x * EPB;
    unsigned pay[16];
    short bk[16], pib[16];
#pragma unroll
    for (int j = 0; j < 16; ++j) {
        int e = base + j * 256 + t;
        int d = ei[N_EDGES + e];
        int s = ei[e];
        bk[j] = (short)(d >> 8);
        pay[j] = (unsigned)(d & 255) | ((unsigned)s << 8);
        pib[j] = (short)atomicAdd(&cur[d >> 8], 1);
    }
    __syncthreads();
    for (int i = t; i < NBKT; i += 256) {
        int c = cur[i];
        gb[i] = c ? atomicAdd(&gcur[i * 16], c) : 0;  // line-padded cursor
    }
    __syncthreads();
#pragma unroll
    for (int j = 0; j < 16; ++j) {
        int pos = gb[bk[j]] + pib[j];
        if (pos < BCAP) gbuf[bk[j] * BCAP + pos] = pay[j];
    }
}

// ---------------- pass 2: per-bucket CSR build (+ dinv, fused) ----------------
__global__ __launch_bounds__(256) void k_bcsr(const int* __restrict__ gcur,
                                              const unsigned* __restrict__ gbuf,
                                              int* __restrict__ adj,
                                              unsigned* __restrict__ co,
                                              float* __restrict__ dinv) {
    __shared__ int hist[256];
    __shared__ int arr[256];
    __shared__ int exc[256];
    const int b = blockIdx.x, t = threadIdx.x;
    hist[t] = 0;
    __syncthreads();
    int E = gcur[b * 16];
    if (E > BCAP) E = BCAP;
    int dl[10], sv[10];
    short pb[10];
    int n = 0;
    for (int idx = t; idx < E; idx += 256) {
        unsigned p = gbuf[b * BCAP + idx];
        dl[n] = p & 255;
        sv[n] = (int)(p >> 8);
        pb[n] = (short)atomicAdd(&hist[dl[n]], 1);
        ++n;
    }
    __syncthreads();
    const int cnt_t = hist[t];
    arr[t] = cnt_t;
    __syncthreads();
    for (int d = 1; d < 256; d <<= 1) {      // Hillis-Steele inclusive scan
        int v = (t >= d) ? arr[t - d] : 0;
        __syncthreads();
        arr[t] += v;
        __syncthreads();
    }
    const int ex = arr[t] - cnt_t;           // exclusive offset
    exc[t] = ex;
    const int node = b * 256 + t;
    co[node] = ((unsigned)ex << 16) | (unsigned)cnt_t;
    dinv[node] = rsqrtf((float)cnt_t + 1.0f);
    __syncthreads();
    for (int j = 0; j < n; ++j)
        adj[b * BCAP + exc[dl[j]] + pb[j]] = sv[j];
}

// ---------------- x f32 -> bf16 copy (4 elems/thread) ----------------
__global__ __launch_bounds__(256) void k_xtobf(const float* __restrict__ x,
                                               bf16* __restrict__ xb) {
    int t = blockIdx.x * 256 + threadIdx.x;
    const float4 v = ((const float4*)x)[t];
    bf16* o = xb + t * 4;
    o[0] = __float2bfloat16(v.x);
    o[1] = __float2bfloat16(v.y);
    o[2] = __float2bfloat16(v.z);
    o[3] = __float2bfloat16(v.w);
}

// ---------------- weight conversion (f32 -> bf16, transposed) ----------------
__global__ __launch_bounds__(256) void k_convw(const float* __restrict__ W1,
                                               const float* __restrict__ W2,
                                               bf16* __restrict__ W1T,
                                               bf16* __restrict__ W2T) {
    int t = blockIdx.x * 256 + threadIdx.x;
    if (t < 64 * 128) {                 // W1 [64][128] -> W1T [128][64]
        int k = t >> 7, n = t & 127;
        W1T[n * 64 + k] = __float2bfloat16(W1[t]);
    } else {                            // W2 [128][64] -> W2T [64][128]
        int u = t - 64 * 128;
        int k = u >> 6, n = u & 63;
        W2T[n * 128 + k] = __float2bfloat16(W2[u]);
    }
}

// Wfc [1920][1728] f32 -> WfcT [1728][1920] bf16
__global__ __launch_bounds__(256) void k_transWfc(const float* __restrict__ W,
                                                  bf16* __restrict__ WT) {
    __shared__ float t[32][33];
    int tx = threadIdx.x, ty = threadIdx.y;
    int n0 = blockIdx.x * 32, k0 = blockIdx.y * 32;
#pragma unroll
    for (int j = 0; j < 4; ++j)
        t[ty + j * 8][tx] = W[(long)(k0 + ty + j * 8) * 1728 + n0 + tx];
    __syncthreads();
#pragma unroll
    for (int j = 0; j < 4; ++j)
        WT[(long)(n0 + ty + j * 8) * 1920 + k0 + tx] =
            __float2bfloat16(t[tx][ty + j * 8]);
}

// ---------------- aggregation: 4 nodes/wave, 16 lanes x 4 feats ----------------
// One load instruction covers 4 rows (4 nodes x 16 lanes x 8 B) -> 32 rows in
// flight per wave with the 8-deep batch; half the wave count of the 2-node
// version.
template <bool BIAS_RELU>
__global__ __launch_bounds__(256) void k_agg(const bf16* __restrict__ xb,
                                             const float* __restrict__ dinv,
                                             const unsigned* __restrict__ co,
                                             const int* __restrict__ adj,
                                             const float* __restrict__ bias,
                                             bf16* __restrict__ out) {
    const int wave = threadIdx.x >> 6, lane = threadIdx.x & 63;
    const int sub = lane >> 4, l16 = lane & 15;
    const int node = blockIdx.x * 16 + wave * 4 + sub;

    const float di = dinv[node];
    const unsigned c_ = co[node];
    int c = (int)(c_ & 0xffffu);
    if (c > 32) c = 32;
    const int* al = adj + (node >> 8) * BCAP + (c_ >> 16);
    int   sl  = (l16 < c)      ? al[l16]      : 0;
    int   sl2 = (16 + l16 < c) ? al[16 + l16] : 0;
    float wl  = (l16 < c)      ? dinv[sl]     : 0.0f;
    float wl2 = (16 + l16 < c) ? dinv[sl2]    : 0.0f;

    const uint2 us = *(const uint2*)(xb + ((long)node << 6) + (l16 << 2));
    float a0 = di * bflo(us.x), a1 = di * bfhi(us.x);
    float a2 = di * bflo(us.y), a3 = di * bfhi(us.y);

    for (int p0 = 0; p0 < c; p0 += 8) {
        uint2 uu[8];
        float w8[8];
#pragma unroll
        for (int j = 0; j < 8; ++j) {
            int p = p0 + j;
            bool ok = p < c;                 // uniform within 16-lane group
            int   sv = (p < 16) ? sl : sl2;
            float wv = (p < 16) ? wl : wl2;
            int s = ok ? __shfl(sv, p & 15, 16) : 0;  // row 0 stays L1-hot
            w8[j] = ok ? __shfl(wv, p & 15, 16) : 0.0f;
            uu[j] = *(const uint2*)(xb + ((long)s << 6) + (l16 << 2));
        }
#pragma unroll
        for (int j = 0; j < 8; ++j) {
            a0 += w8[j] * bflo(uu[j].x);
            a1 += w8[j] * bfhi(uu[j].x);
            a2 += w8[j] * bflo(uu[j].y);
            a3 += w8[j] * bfhi(uu[j].y);
        }
    }

    float r0 = di * a0, r1 = di * a1, r2 = di * a2, r3 = di * a3;
    if (BIAS_RELU) {
        r0 = fmaxf(r0 + bias[l16 * 4 + 0], 0.0f);
        r1 = fmaxf(r1 + bias[l16 * 4 + 1], 0.0f);
        r2 = fmaxf(r2 + bias[l16 * 4 + 2], 0.0f);
        r3 = fmaxf(r3 + bias[l16 * 4 + 3], 0.0f);
    }
    bf16* o = out + ((long)node << 6) + (l16 << 2);
    o[0] = __float2bfloat16(r0);
    o[1] = __float2bfloat16(r1);
    o[2] = __float2bfloat16(r2);
    o[3] = __float2bfloat16(r3);
}

// ---------------- fused MLP: g = relu(xa@W1 + b1) @ W2 ----------------
__global__ __launch_bounds__(256) void k_mlp(const bf16* __restrict__ xa,
                                             const bf16* __restrict__ W1T,
                                             const bf16* __restrict__ W2T,
                                             const float* __restrict__ b1,
                                             bf16* __restrict__ g) {
    __shared__ __align__(16) bf16 As[128 * 64];    // row&7 chunk-XOR swizzle
    __shared__ __align__(16) bf16 C1s[128 * 136];
    const int tid = threadIdx.x;
    const int wave = tid >> 6, lane = tid & 63;
    const int quad = lane >> 4, l16 = lane & 15;
    const int bm = blockIdx.x * 128;
    const int wm = (wave & 1) * 64;
    const int wn1 = (wave >> 1) * 64;
    const int wn2 = (wave >> 1) * 32;

#pragma unroll
    for (int q = 0; q < 4; ++q) {
        int G = q * 256 + tid;
        int gc = (G & ~7) | ((G & 7) ^ ((G >> 3) & 7));
        gl_lds16(xa + (long)bm * 64 + gc * 8, As + ((q * 4 + wave) * 64) * 8);
    }
    short8 w1f[2][4];
#pragma unroll
    for (int kc = 0; kc < 2; ++kc)
#pragma unroll
        for (int in = 0; in < 4; ++in)
            w1f[kc][in] = *(const short8*)(W1T + (wn1 + in * 16 + l16) * 64 +
                                           kc * 32 + quad * 8);
    floatx4 acc1[4][4];
#pragma unroll
    for (int i = 0; i < 4; ++i)
#pragma unroll
        for (int j = 0; j < 4; ++j) acc1[i][j] = (floatx4){0.f, 0.f, 0.f, 0.f};
    __syncthreads();

#pragma unroll
    for (int kc = 0; kc < 2; ++kc)
#pragma unroll
        for (int im = 0; im < 4; ++im) {
            const int R = wm + im * 16 + l16;
            short8 af = *(const short8*)(As + R * 64 +
                                         (((kc * 4 + quad) ^ (R & 7)) * 8));
#pragma unroll
            for (int in = 0; in < 4; ++in)
                acc1[im][in] = __builtin_amdgcn_mfma_f32_16x16x32_bf16(
                    af, w1f[kc][in], acc1[im][in], 0, 0, 0);
        }

#pragma unroll
    for (int in = 0; in < 4; ++in) {
        const int col = wn1 + in * 16 + l16;
        const float bv = b1[col];
#pragma unroll
        for (int im = 0; im < 4; ++im) {
            const int row = wm + im * 16 + quad * 4;
#pragma unroll
            for (int r = 0; r < 4; ++r)
                C1s[(row + r) * 136 + col] =
                    __float2bfloat16(fmaxf(acc1[im][in][r] + bv, 0.0f));
        }
    }
    short8 w2f[4][2];
#pragma unroll
    for (int kc = 0; kc < 4; ++kc)
#pragma unroll
        for (int in = 0; in < 2; ++in)
            w2f[kc][in] = *(const short8*)(W2T + (wn2 + in * 16 + l16) * 128 +
                                           kc * 32 + quad * 8);
    floatx4 acc2[4][2];
#pragma unroll
    for (int i = 0; i < 4; ++i)
#pragma unroll
        for (int j = 0; j < 2; ++j) acc2[i][j] = (floatx4){0.f, 0.f, 0.f, 0.f};
    __syncthreads();

#pragma unroll
    for (int kc = 0; kc < 4; ++kc)
#pragma unroll
        for (int im = 0; im < 4; ++im) {
            short8 af = *(const short8*)(C1s + (wm + im * 16 + l16) * 136 +
                                         kc * 32 + quad * 8);
#pragma unroll
            for (int in = 0; in < 2; ++in)
                acc2[im][in] = __builtin_amdgcn_mfma_f32_16x16x32_bf16(
                    af, w2f[kc][in], acc2[im][in], 0, 0, 0);
        }

#pragma unroll
    for (int in = 0; in < 2; ++in) {
        const int col = wn2 + in * 16 + l16;
#pragma unroll
        for (int im = 0; im < 4; ++im) {
            const int row = bm + wm + im * 16 + quad * 4;
#pragma unroll
            for (int r = 0; r < 4; ++r)
                g[(long)(row + r) * 64 + col] = __float2bfloat16(acc2[im][in][r]);
        }
    }
}

// ---------------- bf16 MFMA GEMM, depth-1 register pipeline (round-8) ----------
// Depth-2 spilled to scratch (r9: WRITE 28->493 MB, VGPR capped at 48). Depth-1
// is the plateau for this 2-barrier structure; do not deepen without
// restructuring the K-loop.
template <bool RELU, bool BIAS, typename OutT>
__global__ __launch_bounds__(256) void gemm_bt(const bf16* __restrict__ A,
                                               const bf16* __restrict__ BT,
                                               const float* __restrict__ bias,
                                               OutT* __restrict__ C,
                                               int M, int N, int K) {
    __shared__ __align__(16) bf16 As[128 * 32];
    __shared__ __align__(16) bf16 Bs[64 * 32];
    const int tid = threadIdx.x;
    const int wave = tid >> 6, lane = tid & 63;
    const int quad = lane >> 4, l16 = lane & 15;
    const int bm = blockIdx.x * 128, bn = blockIdx.y * 64;
    const int wm = (wave & 1) * 64, wn = (wave >> 1) * 32;

    floatx4 acc[4][2];
#pragma unroll
    for (int i = 0; i < 4; ++i)
#pragma unroll
        for (int j = 0; j < 2; ++j) acc[i][j] = (floatx4){0.f, 0.f, 0.f, 0.f};

    const int r4 = tid >> 2;   // row 0..63 within half-tile
    const int cc = tid & 3;    // linear global chunk
    const int slot = r4 * 32 + ((cc ^ ((r4 >> 1) & 3)) * 8);  // swizzled (shorts)

    const bf16* gA0 = A + (long)(bm + r4) * K + cc * 8;
    const bf16* gA1 = A + (long)(bm + r4 + 64) * K + cc * 8;
    const bf16* gB  = BT + (long)(bn + r4) * K + cc * 8;

    uint4 ra0 = *(const uint4*)gA0;
    uint4 ra1 = *(const uint4*)gA1;
    uint4 rb  = *(const uint4*)gB;

    const int rsw = (l16 >> 1) & 3;

    for (int k0 = 0; k0 < K; k0 += 32) {
        *(uint4*)(As + slot) = ra0;
        *(uint4*)(As + 2048 + slot) = ra1;
        *(uint4*)(Bs + slot) = rb;
        __syncthreads();
        if (k0 + 32 < K) {   // prefetch next tile; consumed at next ds_write
            ra0 = *(const uint4*)(gA0 + k0 + 32);
            ra1 = *(const uint4*)(gA1 + k0 + 32);
            rb  = *(const uint4*)(gB + k0 + 32);
        }
        short8 af[4], bfr[2];
#pragma unroll
        for (int im = 0; im < 4; ++im)
            af[im] = *(const short8*)(As + (wm + im * 16 + l16) * 32 +
                                      (quad ^ rsw) * 8);
#pragma unroll
        for (int in = 0; in < 2; ++in)
            bfr[in] = *(const short8*)(Bs + (wn + in * 16 + l16) * 32 +
                                       (quad ^ rsw) * 8);
#pragma unroll
        for (int im = 0; im < 4; ++im)
#pragma unroll
            for (int in = 0; in < 2; ++in)
                acc[im][in] = __builtin_amdgcn_mfma_f32_16x16x32_bf16(
                    af[im], bfr[in], acc[im][in], 0, 0, 0);
        __syncthreads();
    }

#pragma unroll
    for (int in = 0; in < 2; ++in) {
        int gcol = bn + wn + in * 16 + l16;
        float bv = BIAS ? bias[gcol] : 0.0f;
#pragma unroll
        for (int im = 0; im < 4; ++im) {
            int mrow = bm + wm + im * 16 + quad * 4;
#pragma unroll
            for (int r = 0; r < 4; ++r) {
                float v = acc[im][in][r] + bv;
                if (RELU) v = fmaxf(v, 0.0f);
                if constexpr (sizeof(OutT) == 2)
                    C[(long)(mrow + r) * N + gcol] = __float2bfloat16(v);
                else
                    C[(long)(mrow + r) * N + gcol] = v;
            }
        }
    }
}

// ---------------- driver ----------------
extern "C" void kernel_launch(void* const* d_in, const int* in_sizes, int n_in,
                              void* d_out, int out_size, void* d_ws, size_t ws_size,
                              hipStream_t stream) {
    const float* x   = (const float*)d_in[0];
    const int*   ei  = (const int*)d_in[1];
    const float* W1  = (const float*)d_in[2];
    const float* b1  = (const float*)d_in[3];
    const float* W2  = (const float*)d_in[4];
    const float* b2  = (const float*)d_in[5];
    const float* Wfc = (const float*)d_in[6];
    const float* bfc = (const float*)d_in[7];

    char* p = (char*)d_ws;
    int*      gcur = (int*)p;      p += (size_t)NBKT * 16 * 4;
    unsigned* gbuf = (unsigned*)p; p += (size_t)NBKT * BCAP * 4;
    int*      adj  = (int*)p;      p += (size_t)NBKT * BCAP * 4;
    unsigned* co   = (unsigned*)p; p += (size_t)N_NODES * 4;
    float*    dinv = (float*)p;    p += (size_t)N_NODES * 4;
    bf16*     xb   = (bf16*)p;     p += (size_t)N_NODES * 64 * 2;
    bf16*     xa   = (bf16*)p;     p += (size_t)N_NODES * 64 * 2;
    bf16*     g    = (bf16*)p;     p += (size_t)N_NODES * 64 * 2;
    bf16*     h2   = (bf16*)p;     p += (size_t)N_NODES * 64 * 2;
    bf16*     W1T  = (bf16*)p;     p += 128 * 64 * 2;
    bf16*     W2T  = (bf16*)p;     p += 64 * 128 * 2;
    bf16*     WfcT = (bf16*)p;     p += (size_t)1728 * 1920 * 2;

    hipMemsetAsync(gcur, 0, (size_t)NBKT * 16 * 4, stream);
    k_psort<<<N_EDGES / EPB, 256, 0, stream>>>(ei, gcur, gbuf);
    k_bcsr<<<NBKT, 256, 0, stream>>>(gcur, gbuf, adj, co, dinv);
    k_xtobf<<<N_NODES * 64 / 4 / 256, 256, 0, stream>>>(x, xb);
    k_convw<<<64, 256, 0, stream>>>(W1, W2, W1T, W2T);
    k_transWfc<<<dim3(54, 60), dim3(32, 8), 0, stream>>>(Wfc, WfcT);

    // xa = A_hat * x
    k_agg<false><<<N_NODES / 16, 256, 0, stream>>>(xb, dinv, co, adj, nullptr, xa);
    // g = relu(xa@W1 + b1) @ W2   (fused, h1 never touches HBM)
    k_mlp<<<N_NODES / 128, 256, 0, stream>>>(xa, W1T, W2T, b1, g);
    // h2 = relu(A_hat * g + b2)
    k_agg<true><<<N_NODES / 16, 256, 0, stream>>>(g, dinv, co, adj, b2, h2);
    // out = h2.reshape(4096,1920) @ Wfc + bfc
    gemm_bt<false, true, float><<<dim3(32, 27), 256, 0, stream>>>(
        h2, WfcT, bfc, (float*)d_out, 4096, 1728, 1920);
}

// Round 11
// 244.921 us; speedup vs baseline: 1.6958x; 1.0025x over previous
//
#include <hip/hip_runtime.h>
#include <hip/hip_bf16.h>

#define N_NODES 122880
#define N_EDGES 983040
#define NBKT 480      // buckets of 256 nodes
#define BCAP 2560     // per-bucket edge capacity (mean 2048, +11 sigma)
#define EPB 4096      // edges per pass-1 block

typedef __hip_bfloat16 bf16;
typedef __attribute__((ext_vector_type(8))) short short8;
typedef __attribute__((ext_vector_type(4))) float floatx4;

__device__ __forceinline__ void gl_lds16(const void* g, void* l) {
    __builtin_amdgcn_global_load_lds(
        (const __attribute__((address_space(1))) void*)g,
        (__attribute__((address_space(3))) void*)l, 16, 0, 0);
}

__device__ __forceinline__ float bflo(unsigned u) {
    return __uint_as_float(u << 16);
}
__device__ __forceinline__ float bfhi(unsigned u) {
    return __uint_as_float(u & 0xffff0000u);
}

// ---------------- pass 1: block-local bucket sort of edges ----------------
__global__ __launch_bounds__(256) void k_psort(const int* __restrict__ ei,
                                               int* __restrict__ gcur,
                                               unsigned* __restrict__ gbuf) {
    __shared__ int cur[NBKT];
    __shared__ int gb[NBKT];
    const int t = threadIdx.x;
    for (int i = t; i < NBKT; i += 256) cur[i] = 0;
    __syncthreads();
    const int base = blockIdx.x * EPB;
    unsigned pay[16];
    short bk[16], pib[16];
#pragma unroll
    for (int j = 0; j < 16; ++j) {
        int e = base + j * 256 + t;
        int d = ei[N_EDGES + e];
        int s = ei[e];
        bk[j] = (short)(d >> 8);
        pay[j] = (unsigned)(d & 255) | ((unsigned)s << 8);
        pib[j] = (short)atomicAdd(&cur[d >> 8], 1);
    }
    __syncthreads();
    for (int i = t; i < NBKT; i += 256) {
        int c = cur[i];
        gb[i] = c ? atomicAdd(&gcur[i * 16], c) : 0;  // line-padded cursor
    }
    __syncthreads();
#pragma unroll
    for (int j = 0; j < 16; ++j) {
        int pos = gb[bk[j]] + pib[j];
        if (pos < BCAP) gbuf[bk[j] * BCAP + pos] = pay[j];
    }
}

// ---------------- pass 2: per-bucket CSR build (+ dinv, fused) ----------------
__global__ __launch_bounds__(256) void k_bcsr(const int* __restrict__ gcur,
                                              const unsigned* __restrict__ gbuf,
                                              int* __restrict__ adj,
                                              unsigned* __restrict__ co,
                                              float* __restrict__ dinv) {
    __shared__ int hist[256];
    __shared__ int arr[256];
    __shared__ int exc[256];
    const int b = blockIdx.x, t = threadIdx.x;
    hist[t] = 0;
    __syncthreads();
    int E = gcur[b * 16];
    if (E > BCAP) E = BCAP;
    int dl[10], sv[10];
    short pb[10];
    int n = 0;
    for (int idx = t; idx < E; idx += 256) {
        unsigned p = gbuf[b * BCAP + idx];
        dl[n] = p & 255;
        sv[n] = (int)(p >> 8);
        pb[n] = (short)atomicAdd(&hist[dl[n]], 1);
        ++n;
    }
    __syncthreads();
    const int cnt_t = hist[t];
    arr[t] = cnt_t;
    __syncthreads();
    for (int d = 1; d < 256; d <<= 1) {      // Hillis-Steele inclusive scan
        int v = (t >= d) ? arr[t - d] : 0;
        __syncthreads();
        arr[t] += v;
        __syncthreads();
    }
    const int ex = arr[t] - cnt_t;           // exclusive offset
    exc[t] = ex;
    const int node = b * 256 + t;
    co[node] = ((unsigned)ex << 16) | (unsigned)cnt_t;
    dinv[node] = rsqrtf((float)cnt_t + 1.0f);
    __syncthreads();
    for (int j = 0; j < n; ++j)
        adj[b * BCAP + exc[dl[j]] + pb[j]] = sv[j];
}

// ---------------- x f32 -> bf16 copy (4 elems/thread) ----------------
__global__ __launch_bounds__(256) void k_xtobf(const float* __restrict__ x,
                                               bf16* __restrict__ xb) {
    int t = blockIdx.x * 256 + threadIdx.x;
    const float4 v = ((const float4*)x)[t];
    bf16* o = xb + t * 4;
    o[0] = __float2bfloat16(v.x);
    o[1] = __float2bfloat16(v.y);
    o[2] = __float2bfloat16(v.z);
    o[3] = __float2bfloat16(v.w);
}

// ---------------- weight conversion (f32 -> bf16, transposed) ----------------
__global__ __launch_bounds__(256) void k_convw(const float* __restrict__ W1,
                                               const float* __restrict__ W2,
                                               bf16* __restrict__ W1T,
                                               bf16* __restrict__ W2T) {
    int t = blockIdx.x * 256 + threadIdx.x;
    if (t < 64 * 128) {                 // W1 [64][128] -> W1T [128][64]
        int k = t >> 7, n = t & 127;
        W1T[n * 64 + k] = __float2bfloat16(W1[t]);
    } else {                            // W2 [128][64] -> W2T [64][128]
        int u = t - 64 * 128;
        int k = u >> 6, n = u & 63;
        W2T[n * 128 + k] = __float2bfloat16(W2[u]);
    }
}

// Wfc [1920][1728] f32 -> WfcT [1728][1920] bf16
__global__ __launch_bounds__(256) void k_transWfc(const float* __restrict__ W,
                                                  bf16* __restrict__ WT) {
    __shared__ float t[32][33];
    int tx = threadIdx.x, ty = threadIdx.y;
    int n0 = blockIdx.x * 32, k0 = blockIdx.y * 32;
#pragma unroll
    for (int j = 0; j < 4; ++j)
        t[ty + j * 8][tx] = W[(long)(k0 + ty + j * 8) * 1728 + n0 + tx];
    __syncthreads();
#pragma unroll
    for (int j = 0; j < 4; ++j)
        WT[(long)(n0 + ty + j * 8) * 1920 + k0 + tx] =
            __float2bfloat16(t[tx][ty + j * 8]);
}

// ---------------- aggregation: 4 nodes/wave, 16 lanes x 4 feats ----------------
template <bool BIAS_RELU>
__global__ __launch_bounds__(256) void k_agg(const bf16* __restrict__ xb,
                                             const float* __restrict__ dinv,
                                             const unsigned* __restrict__ co,
                                             const int* __restrict__ adj,
                                             const float* __restrict__ bias,
                                             bf16* __restrict__ out) {
    const int wave = threadIdx.x >> 6, lane = threadIdx.x & 63;
    const int sub = lane >> 4, l16 = lane & 15;
    const int node = blockIdx.x * 16 + wave * 4 + sub;

    const float di = dinv[node];
    const unsigned c_ = co[node];
    int c = (int)(c_ & 0xffffu);
    if (c > 32) c = 32;
    const int* al = adj + (node >> 8) * BCAP + (c_ >> 16);
    int   sl  = (l16 < c)      ? al[l16]      : 0;
    int   sl2 = (16 + l16 < c) ? al[16 + l16] : 0;
    float wl  = (l16 < c)      ? dinv[sl]     : 0.0f;
    float wl2 = (16 + l16 < c) ? dinv[sl2]    : 0.0f;

    const uint2 us = *(const uint2*)(xb + ((long)node << 6) + (l16 << 2));
    float a0 = di * bflo(us.x), a1 = di * bfhi(us.x);
    float a2 = di * bflo(us.y), a3 = di * bfhi(us.y);

    for (int p0 = 0; p0 < c; p0 += 8) {
        uint2 uu[8];
        float w8[8];
#pragma unroll
        for (int j = 0; j < 8; ++j) {
            int p = p0 + j;
            bool ok = p < c;                 // uniform within 16-lane group
            int   sv = (p < 16) ? sl : sl2;
            float wv = (p < 16) ? wl : wl2;
            int s = ok ? __shfl(sv, p & 15, 16) : 0;  // row 0 stays L1-hot
            w8[j] = ok ? __shfl(wv, p & 15, 16) : 0.0f;
            uu[j] = *(const uint2*)(xb + ((long)s << 6) + (l16 << 2));
        }
#pragma unroll
        for (int j = 0; j < 8; ++j) {
            a0 += w8[j] * bflo(uu[j].x);
            a1 += w8[j] * bfhi(uu[j].x);
            a2 += w8[j] * bflo(uu[j].y);
            a3 += w8[j] * bfhi(uu[j].y);
        }
    }

    float r0 = di * a0, r1 = di * a1, r2 = di * a2, r3 = di * a3;
    if (BIAS_RELU) {
        r0 = fmaxf(r0 + bias[l16 * 4 + 0], 0.0f);
        r1 = fmaxf(r1 + bias[l16 * 4 + 1], 0.0f);
        r2 = fmaxf(r2 + bias[l16 * 4 + 2], 0.0f);
        r3 = fmaxf(r3 + bias[l16 * 4 + 3], 0.0f);
    }
    bf16* o = out + ((long)node << 6) + (l16 << 2);
    o[0] = __float2bfloat16(r0);
    o[1] = __float2bfloat16(r1);
    o[2] = __float2bfloat16(r2);
    o[3] = __float2bfloat16(r3);
}

// ---------------- fused MLP: g = relu(xa@W1 + b1) @ W2 ----------------
__global__ __launch_bounds__(256) void k_mlp(const bf16* __restrict__ xa,
                                             const bf16* __restrict__ W1T,
                                             const bf16* __restrict__ W2T,
                                             const float* __restrict__ b1,
                                             bf16* __restrict__ g) {
    __shared__ __align__(16) bf16 As[128 * 64];    // row&7 chunk-XOR swizzle
    __shared__ __align__(16) bf16 C1s[128 * 136];
    const int tid = threadIdx.x;
    const int wave = tid >> 6, lane = tid & 63;
    const int quad = lane >> 4, l16 = lane & 15;
    const int bm = blockIdx.x * 128;
    const int wm = (wave & 1) * 64;
    const int wn1 = (wave >> 1) * 64;
    const int wn2 = (wave >> 1) * 32;

#pragma unroll
    for (int q = 0; q < 4; ++q) {
        int G = q * 256 + tid;
        int gc = (G & ~7) | ((G & 7) ^ ((G >> 3) & 7));
        gl_lds16(xa + (long)bm * 64 + gc * 8, As + ((q * 4 + wave) * 64) * 8);
    }
    short8 w1f[2][4];
#pragma unroll
    for (int kc = 0; kc < 2; ++kc)
#pragma unroll
        for (int in = 0; in < 4; ++in)
            w1f[kc][in] = *(const short8*)(W1T + (wn1 + in * 16 + l16) * 64 +
                                           kc * 32 + quad * 8);
    floatx4 acc1[4][4];
#pragma unroll
    for (int i = 0; i < 4; ++i)
#pragma unroll
        for (int j = 0; j < 4; ++j) acc1[i][j] = (floatx4){0.f, 0.f, 0.f, 0.f};
    __syncthreads();

#pragma unroll
    for (int kc = 0; kc < 2; ++kc)
#pragma unroll
        for (int im = 0; im < 4; ++im) {
            const int R = wm + im * 16 + l16;
            short8 af = *(const short8*)(As + R * 64 +
                                         (((kc * 4 + quad) ^ (R & 7)) * 8));
#pragma unroll
            for (int in = 0; in < 4; ++in)
                acc1[im][in] = __builtin_amdgcn_mfma_f32_16x16x32_bf16(
                    af, w1f[kc][in], acc1[im][in], 0, 0, 0);
        }

#pragma unroll
    for (int in = 0; in < 4; ++in) {
        const int col = wn1 + in * 16 + l16;
        const float bv = b1[col];
#pragma unroll
        for (int im = 0; im < 4; ++im) {
            const int row = wm + im * 16 + quad * 4;
#pragma unroll
            for (int r = 0; r < 4; ++r)
                C1s[(row + r) * 136 + col] =
                    __float2bfloat16(fmaxf(acc1[im][in][r] + bv, 0.0f));
        }
    }
    short8 w2f[4][2];
#pragma unroll
    for (int kc = 0; kc < 4; ++kc)
#pragma unroll
        for (int in = 0; in < 2; ++in)
            w2f[kc][in] = *(const short8*)(W2T + (wn2 + in * 16 + l16) * 128 +
                                           kc * 32 + quad * 8);
    floatx4 acc2[4][2];
#pragma unroll
    for (int i = 0; i < 4; ++i)
#pragma unroll
        for (int j = 0; j < 2; ++j) acc2[i][j] = (floatx4){0.f, 0.f, 0.f, 0.f};
    __syncthreads();

#pragma unroll
    for (int kc = 0; kc < 4; ++kc)
#pragma unroll
        for (int im = 0; im < 4; ++im) {
            short8 af = *(const short8*)(C1s + (wm + im * 16 + l16) * 136 +
                                         kc * 32 + quad * 8);
#pragma unroll
            for (int in = 0; in < 2; ++in)
                acc2[im][in] = __builtin_amdgcn_mfma_f32_16x16x32_bf16(
                    af, w2f[kc][in], acc2[im][in], 0, 0, 0);
        }

#pragma unroll
    for (int in = 0; in < 2; ++in) {
        const int col = wn2 + in * 16 + l16;
#pragma unroll
        for (int im = 0; im < 4; ++im) {
            const int row = bm + wm + im * 16 + quad * 4;
#pragma unroll
            for (int r = 0; r < 4; ++r)
                g[(long)(row + r) * 64 + col] = __float2bfloat16(acc2[im][in][r]);
        }
    }
}

// ---------------- bf16 MFMA GEMM, depth-1 pipeline + XCD-affine swizzle ------
// 1-D grid, decode: xcd=bid&7 -> x=(bid&7)*4+((bid>>3)&3), y=bid>>5.
// Under round-robin dispatch each XCD owns 4 M-tiles x 27 N-tiles: A working
// set 1.97 MB < 4 MB L2 -> A re-reads served by L2 instead of LLC (LLC read
// traffic 637 -> ~70 MB). Pure reorder; correct under any dispatch mapping.
template <bool RELU, bool BIAS, typename OutT>
__global__ __launch_bounds__(256) void gemm_bt(const bf16* __restrict__ A,
                                               const bf16* __restrict__ BT,
                                               const float* __restrict__ bias,
                                               OutT* __restrict__ C,
                                               int M, int N, int K) {
    __shared__ __align__(16) bf16 As[128 * 32];
    __shared__ __align__(16) bf16 Bs[64 * 32];
    const int tid = threadIdx.x;
    const int wave = tid >> 6, lane = tid & 63;
    const int quad = lane >> 4, l16 = lane & 15;
    const int bid = blockIdx.x;
    const int bx = (bid & 7) * 4 + ((bid >> 3) & 3);   // M-tile
    const int by = bid >> 5;                           // N-tile
    const int bm = bx * 128, bn = by * 64;
    const int wm = (wave & 1) * 64, wn = (wave >> 1) * 32;

    floatx4 acc[4][2];
#pragma unroll
    for (int i = 0; i < 4; ++i)
#pragma unroll
        for (int j = 0; j < 2; ++j) acc[i][j] = (floatx4){0.f, 0.f, 0.f, 0.f};

    const int r4 = tid >> 2;   // row 0..63 within half-tile
    const int cc = tid & 3;    // linear global chunk
    const int slot = r4 * 32 + ((cc ^ ((r4 >> 1) & 3)) * 8);  // swizzled (shorts)

    const bf16* gA0 = A + (long)(bm + r4) * K + cc * 8;
    const bf16* gA1 = A + (long)(bm + r4 + 64) * K + cc * 8;
    const bf16* gB  = BT + (long)(bn + r4) * K + cc * 8;

    uint4 ra0 = *(const uint4*)gA0;
    uint4 ra1 = *(const uint4*)gA1;
    uint4 rb  = *(const uint4*)gB;

    const int rsw = (l16 >> 1) & 3;

    for (int k0 = 0; k0 < K; k0 += 32) {
        *(uint4*)(As + slot) = ra0;
        *(uint4*)(As + 2048 + slot) = ra1;
        *(uint4*)(Bs + slot) = rb;
        __syncthreads();
        if (k0 + 32 < K) {   // prefetch next tile; consumed at next ds_write
            ra0 = *(const uint4*)(gA0 + k0 + 32);
            ra1 = *(const uint4*)(gA1 + k0 + 32);
            rb  = *(const uint4*)(gB + k0 + 32);
        }
        short8 af[4], bfr[2];
#pragma unroll
        for (int im = 0; im < 4; ++im)
            af[im] = *(const short8*)(As + (wm + im * 16 + l16) * 32 +
                                      (quad ^ rsw) * 8);
#pragma unroll
        for (int in = 0; in < 2; ++in)
            bfr[in] = *(const short8*)(Bs + (wn + in * 16 + l16) * 32 +
                                       (quad ^ rsw) * 8);
#pragma unroll
        for (int im = 0; im < 4; ++im)
#pragma unroll
            for (int in = 0; in < 2; ++in)
                acc[im][in] = __builtin_amdgcn_mfma_f32_16x16x32_bf16(
                    af[im], bfr[in], acc[im][in], 0, 0, 0);
        __syncthreads();
    }

#pragma unroll
    for (int in = 0; in < 2; ++in) {
        int gcol = bn + wn + in * 16 + l16;
        float bv = BIAS ? bias[gcol] : 0.0f;
#pragma unroll
        for (int im = 0; im < 4; ++im) {
            int mrow = bm + wm + im * 16 + quad * 4;
#pragma unroll
            for (int r = 0; r < 4; ++r) {
                float v = acc[im][in][r] + bv;
                if (RELU) v = fmaxf(v, 0.0f);
                if constexpr (sizeof(OutT) == 2)
                    C[(long)(mrow + r) * N + gcol] = __float2bfloat16(v);
                else
                    C[(long)(mrow + r) * N + gcol] = v;
            }
        }
    }
}

// ---------------- driver ----------------
extern "C" void kernel_launch(void* const* d_in, const int* in_sizes, int n_in,
                              void* d_out, int out_size, void* d_ws, size_t ws_size,
                              hipStream_t stream) {
    const float* x   = (const float*)d_in[0];
    const int*   ei  = (const int*)d_in[1];
    const float* W1  = (const float*)d_in[2];
    const float* b1  = (const float*)d_in[3];
    const float* W2  = (const float*)d_in[4];
    const float* b2  = (const float*)d_in[5];
    const float* Wfc = (const float*)d_in[6];
    const float* bfc = (const float*)d_in[7];

    char* p = (char*)d_ws;
    int*      gcur = (int*)p;      p += (size_t)NBKT * 16 * 4;
    unsigned* gbuf = (unsigned*)p; p += (size_t)NBKT * BCAP * 4;
    int*      adj  = (int*)p;      p += (size_t)NBKT * BCAP * 4;
    unsigned* co   = (unsigned*)p; p += (size_t)N_NODES * 4;
    float*    dinv = (float*)p;    p += (size_t)N_NODES * 4;
    bf16*     xb   = (bf16*)p;     p += (size_t)N_NODES * 64 * 2;
    bf16*     xa   = (bf16*)p;     p += (size_t)N_NODES * 64 * 2;
    bf16*     g    = (bf16*)p;     p += (size_t)N_NODES * 64 * 2;
    bf16*     h2   = (bf16*)p;     p += (size_t)N_NODES * 64 * 2;
    bf16*     W1T  = (bf16*)p;     p += 128 * 64 * 2;
    bf16*     W2T  = (bf16*)p;     p += 64 * 128 * 2;
    bf16*     WfcT = (bf16*)p;     p += (size_t)1728 * 1920 * 2;

    hipMemsetAsync(gcur, 0, (size_t)NBKT * 16 * 4, stream);
    k_psort<<<N_EDGES / EPB, 256, 0, stream>>>(ei, gcur, gbuf);
    k_bcsr<<<NBKT, 256, 0, stream>>>(gcur, gbuf, adj, co, dinv);
    k_xtobf<<<N_NODES * 64 / 4 / 256, 256, 0, stream>>>(x, xb);
    k_convw<<<64, 256, 0, stream>>>(W1, W2, W1T, W2T);
    k_transWfc<<<dim3(54, 60), dim3(32, 8), 0, stream>>>(Wfc, WfcT);

    // xa = A_hat * x
    k_agg<false><<<N_NODES / 16, 256, 0, stream>>>(xb, dinv, co, adj, nullptr, xa);
    // g = relu(xa@W1 + b1) @ W2   (fused, h1 never touches HBM)
    k_mlp<<<N_NODES / 128, 256, 0, stream>>>(xa, W1T, W2T, b1, g);
    // h2 = relu(A_hat * g + b2)
    k_agg<true><<<N_NODES / 16, 256, 0, stream>>>(g, dinv, co, adj, b2, h2);
    // out = h2.reshape(4096,1920) @ Wfc + bfc  (XCD-affine 1-D grid: 32x27=864)
    gemm_bt<false, true, float><<<864, 256, 0, stream>>>(
        h2, WfcT, bfc, (float*)d_out, 4096, 1728, 1920);
}